// Round 1
// baseline (657.062 us; speedup 1.0000x reference)
//
#include <hip/hip_runtime.h>
#include <hip/hip_bf16.h>

typedef unsigned short u16;
typedef unsigned int u32;

#define N_TOK 4096
#define DIM   1024
#define HID   4096
#define N_EXP 8
#define CAP   1280

typedef short short8 __attribute__((ext_vector_type(8)));
typedef float f32x4 __attribute__((ext_vector_type(4)));

__device__ __forceinline__ u16 bf16rne(float f) {
    u32 u = __float_as_uint(f);
    u32 r = u + 0x7FFFu + ((u >> 16) & 1u);
    return (u16)(r >> 16);
}
__device__ __forceinline__ float bf2f(u16 h) {
    return __uint_as_float(((u32)h) << 16);
}

#define GLDS(gp, lp) __builtin_amdgcn_global_load_lds( \
    (const __attribute__((address_space(1))) void*)(gp), \
    (__attribute__((address_space(3))) void*)(lp), 16, 0, 0)

// ---------------- Router: one wave per token ----------------
__global__ void router_kernel(const float* __restrict__ x,
                              const float* __restrict__ gw,
                              int* __restrict__ r_eidx,
                              float* __restrict__ r_w) {
    const int wave = threadIdx.x >> 6, lane = threadIdx.x & 63;
    const int t = blockIdx.x * 4 + wave;
    const float* xr = x + (size_t)t * DIM;
    float acc[8];
#pragma unroll
    for (int e = 0; e < 8; e++) acc[e] = 0.f;
#pragma unroll 4
    for (int i = 0; i < DIM / 64; i++) {
        int d = i * 64 + lane;
        float xv = xr[d];
        const float4* g = (const float4*)(gw + (size_t)d * 8);
        float4 g0 = g[0], g1 = g[1];
        acc[0] += xv * g0.x; acc[1] += xv * g0.y;
        acc[2] += xv * g0.z; acc[3] += xv * g0.w;
        acc[4] += xv * g1.x; acc[5] += xv * g1.y;
        acc[6] += xv * g1.z; acc[7] += xv * g1.w;
    }
#pragma unroll
    for (int e = 0; e < 8; e++) {
#pragma unroll
        for (int off = 32; off > 0; off >>= 1)
            acc[e] += __shfl_xor(acc[e], off, 64);
    }
    if (lane == 0) {
        int e0 = 0; float l0 = acc[0];
#pragma unroll
        for (int e = 1; e < 8; e++) if (acc[e] > l0) { l0 = acc[e]; e0 = e; }
        int e1 = -1; float l1 = -1e30f;
#pragma unroll
        for (int e = 0; e < 8; e++) if (e != e0 && acc[e] > l1) { l1 = acc[e]; e1 = e; }
        float z = __expf(l1 - l0);          // <= 1
        float inv = 1.f / (1.f + z);
        r_eidx[t] = e0; r_eidx[N_TOK + t] = e1;
        r_w[t] = inv;   r_w[N_TOK + t] = z * inv;
    }
}

// ---------------- Capacity assignment: single block, deterministic scan ------
__global__ void assign_kernel(const int* __restrict__ r_eidx,
                              int* __restrict__ assign_slot,
                              int* __restrict__ token_for_slot,
                              int* __restrict__ used) {
    const int tid = threadIdx.x;                 // 0..1023
    __shared__ int wtot[8][16];
    __shared__ int wbase[8][16];
    for (int i = tid; i < N_EXP * CAP; i += 1024) token_for_slot[i] = -1;

    int le[8], lr[8], cnt[8];
#pragma unroll
    for (int e = 0; e < 8; e++) cnt[e] = 0;
#pragma unroll
    for (int j = 0; j < 8; j++) {
        int e = r_eidx[tid * 8 + j];
        le[j] = e;
        int r = 0;
#pragma unroll
        for (int e2 = 0; e2 < 8; e2++)
            if (e == e2) { r = cnt[e2]; cnt[e2] = r + 1; }
        lr[j] = r;
    }
    const int lane = tid & 63, wv = tid >> 6;    // 16 waves
    int excl[8];
#pragma unroll
    for (int e = 0; e < 8; e++) {
        int v = cnt[e], inc = v;
#pragma unroll
        for (int off = 1; off < 64; off <<= 1) {
            int u = __shfl_up(inc, off, 64);
            if (lane >= off) inc += u;
        }
        excl[e] = inc - v;
        if (lane == 63) wtot[e][wv] = inc;
    }
    __syncthreads();
    if (tid < 8) {
        int s = 0;
        for (int w = 0; w < 16; w++) { wbase[tid][w] = s; s += wtot[tid][w]; }
        used[tid] = s < CAP ? s : CAP;
    }
    __syncthreads();
#pragma unroll
    for (int j = 0; j < 8; j++) {
        int i = tid * 8 + j;
        int e = le[j];
        int b = 0;
#pragma unroll
        for (int e2 = 0; e2 < 8; e2++)
            if (e == e2) b = wbase[e2][wv] + excl[e2];
        int rank = b + lr[j];
        int tok = i & (N_TOK - 1);
        if (rank < CAP) {
            assign_slot[i] = rank;
            token_for_slot[e * CAP + rank] = tok;
        } else {
            assign_slot[i] = -1;
        }
    }
}

// ---------------- Gather tokens into per-expert batches (bf16) ----------------
__global__ void gather_kernel(const float* __restrict__ x,
                              const int* __restrict__ token_for_slot,
                              u16* __restrict__ exp_batches) {
    const int s = blockIdx.x;
    const int tok = token_for_slot[s];
    const int d = threadIdx.x * 4;
    ushort4 o;
    if (tok >= 0) {
        float4 v = *(const float4*)(x + (size_t)tok * DIM + d);
        o = make_ushort4(bf16rne(v.x), bf16rne(v.y), bf16rne(v.z), bf16rne(v.w));
    } else {
        o = make_ushort4(0, 0, 0, 0);
    }
    *(ushort4*)(exp_batches + (size_t)s * DIM + d) = o;
}

// ---------------- Weight transpose+convert: f32 [R][C] -> bf16 [C][R] --------
__global__ __launch_bounds__(256) void transpose_cvt(
    const float* __restrict__ in, u16* __restrict__ out, int R, int C) {
    __shared__ float t[64][65];
    const int ez = blockIdx.z;
    in  += (size_t)ez * R * C;
    out += (size_t)ez * R * C;
    const int row0 = blockIdx.y * 64, col0 = blockIdx.x * 64;
    const int tid = threadIdx.x;
    {
        const int r = tid >> 2, cq = (tid & 3) * 16;
        const float* p = in + (size_t)(row0 + r) * C + col0 + cq;
        float4 v0 = ((const float4*)p)[0];
        float4 v1 = ((const float4*)p)[1];
        float4 v2 = ((const float4*)p)[2];
        float4 v3 = ((const float4*)p)[3];
        float tmp[16] = {v0.x, v0.y, v0.z, v0.w, v1.x, v1.y, v1.z, v1.w,
                         v2.x, v2.y, v2.z, v2.w, v3.x, v3.y, v3.z, v3.w};
#pragma unroll
        for (int j = 0; j < 16; j++) t[r][cq + j] = tmp[j];
    }
    __syncthreads();
    {
        const int oc = tid >> 2, h4 = (tid & 3) * 16;
        u16 o[16];
#pragma unroll
        for (int i = 0; i < 16; i++) o[i] = bf16rne(t[h4 + i][oc]);
        u16* q = out + (size_t)(col0 + oc) * R + row0 + h4;
        *(uint4*)q = *(const uint4*)&o[0];
        *(uint4*)(q + 8) = *(const uint4*)&o[8];
    }
}

// ---------------- MFMA GEMM, 256x256 tile, 2-phase/K-tile counted-vmcnt ring --
// A: [CAP,K] bf16 row-major per expert.  Bt: [N,K] bf16 row-major (pre-transposed).
// Structure (T3+T4+T5 per guide §5.5): BK=32, 4-slot LDS ring (4 x 32KB = 128KB),
// staging runs 3 K-tiles ahead of compute -> steady-state guard is vmcnt(8)
// (= 2 tiles x 4 loads/thread in flight), issued ONCE per K-tile, never 0 in
// the main loop.  Raw s_barrier (asm, "memory") -- NOT __syncthreads, which
// would re-insert the vmcnt(0) drain this structure exists to remove.
// LDS layout is k-chunk-major [k8][row][8 bf16]: DMA dest = contiguous 1KB per
// wave-load (legal for global_load_lds) and ds_read_b128 frags are 16-lane
// contiguous 256B -> conflict-free with no swizzle.
// Grid: flattened 1D, e = bid&7 (expert<->XCD affinity: each expert's Bt panel
// stays in one XCD's L2), y fastest within XCD so 5 row-tiles reuse one B strip.
// Waves: 8 = 2(M) x 4(N); per-wave C = 128x64 = acc[8][4] frags.
// K-accumulation order identical to previous kernel -> bitwise-same results.
template <bool DO_GELU>
__global__ __launch_bounds__(512, 2) void moe_gemm8(
    const u16* __restrict__ A, const u16* __restrict__ Bt,
    const float* __restrict__ bias, u16* __restrict__ C,
    const int* __restrict__ used, int N, int K) {
    __shared__ __align__(16) u16 lds[4][2][8192];   // [slot][A=0/B=1][16KB/2]

    const int NT = K >> 5;                // K-tiles of 32
    const int bid = blockIdx.x;
    const int e = bid & 7;                // expert == XCD (nwg % 8 == 0)
    const int local = bid >> 3;
    const int row0 = (local % (CAP / 256)) * 256;   // y fastest
    const int col0 = (local / (CAP / 256)) * 256;
    if (row0 >= used[e]) return;          // uniform per block

    A    += (size_t)e * CAP * K;
    Bt   += (size_t)e * N * K;
    bias += (size_t)e * N;
    C    += (size_t)e * CAP * N;

    const int tid = threadIdx.x;
    const int lane = tid & 63, wave = tid >> 6;
    const int wr128 = (wave >> 2) * 128;  // wave's M base in tile
    const int wc64  = (wave & 3) * 64;    // wave's N base in tile

    // staging role: waves 0-3 stage A row-groups 0-3, waves 4-7 stage B
    const int opB = wave >> 2;
    const int rg  = wave & 3;
    const u16* gp = opB ? (Bt + (size_t)(col0 + rg * 64 + lane) * K)
                        : (A  + (size_t)(row0 + rg * 64 + lane) * K);

    f32x4 acc[8][4];
#pragma unroll
    for (int i = 0; i < 8; i++)
#pragma unroll
        for (int j = 0; j < 4; j++) acc[i][j] = (f32x4){0.f, 0.f, 0.f, 0.f};

    // ---- prologue: stage K-tiles 0..2 (12 loads), wait tile 0 (8 newer ok) --
#pragma unroll
    for (int u = 0; u < 3; ++u)
#pragma unroll
        for (int k8 = 0; k8 < 4; ++k8)
            GLDS(gp + u * 32 + k8 * 8, &lds[u][opB][k8 * 2048 + rg * 512]);
    asm volatile("s_waitcnt vmcnt(8)" ::: "memory");
    asm volatile("s_barrier" ::: "memory");

    const int rrd  = lane & 15;           // row-within-16 for frag read
    const int qoff = (lane >> 4) * 2048;  // k8 chunk (u16 units)

    for (int t = 0; t < NT; ++t) {
        const u16* As_s = &lds[t & 3][0][0];
        const u16* Bs_s = &lds[t & 3][1][0];
        const int  t3 = t + 3;
        const bool st = t3 < NT;
        u16* dst = &lds[t3 & 3][opB][rg * 512];
        const u16* src = gp + (size_t)t3 * 32;

        short8 af[4], bfr[4];
        // ---------------- phase 0: M-half 0, all N, k-step t ----------------
#pragma unroll
        for (int j = 0; j < 4; ++j)
            bfr[j] = *(const short8*)(Bs_s + qoff + (wc64 + j * 16 + rrd) * 8);
#pragma unroll
        for (int i = 0; i < 4; ++i)
            af[i] = *(const short8*)(As_s + qoff + (wr128 + i * 16 + rrd) * 8);
        if (st) { GLDS(src, dst); GLDS(src + 8, dst + 2048); }
        asm volatile("s_barrier" ::: "memory");
        __builtin_amdgcn_s_setprio(1);
#pragma unroll
        for (int i = 0; i < 4; ++i)
#pragma unroll
            for (int j = 0; j < 4; ++j)
                acc[i][j] = __builtin_amdgcn_mfma_f32_16x16x32_bf16(
                    af[i], bfr[j], acc[i][j], 0, 0, 0);
        __builtin_amdgcn_s_setprio(0);
        asm volatile("s_barrier" ::: "memory");
        // ---------------- phase 1: M-half 1, B frags reused -----------------
#pragma unroll
        for (int i = 0; i < 4; ++i)
            af[i] = *(const short8*)(As_s + qoff + (wr128 + 64 + i * 16 + rrd) * 8);
        if (st) { GLDS(src + 16, dst + 4096); GLDS(src + 24, dst + 6144); }
        asm volatile("s_barrier" ::: "memory");
        __builtin_amdgcn_s_setprio(1);
#pragma unroll
        for (int i = 0; i < 4; ++i)
#pragma unroll
            for (int j = 0; j < 4; ++j)
                acc[4 + i][j] = __builtin_amdgcn_mfma_f32_16x16x32_bf16(
                    af[i], bfr[j], acc[4 + i][j], 0, 0, 0);
        __builtin_amdgcn_s_setprio(0);
        // guard tile t+1 before next iteration's ds_reads (counted, not 0):
        // outstanding = tiles t+1..min(t+3,NT-1), 4 loads each.
        if (t < NT - 3)       asm volatile("s_waitcnt vmcnt(8)" ::: "memory");
        else if (t == NT - 3) asm volatile("s_waitcnt vmcnt(4)" ::: "memory");
        else if (t == NT - 2) asm volatile("s_waitcnt vmcnt(0)" ::: "memory");
        asm volatile("s_barrier" ::: "memory");
    }

    // ---- epilogue: bias (+gelu, tanh form) -> bf16 ----
    const int cr = (lane >> 4) * 4;
    const int cc = lane & 15;
#pragma unroll
    for (int j = 0; j < 4; ++j) {
        const int col = col0 + wc64 + j * 16 + cc;
        const float bv = bias[col];
#pragma unroll
        for (int i = 0; i < 8; ++i) {
#pragma unroll
            for (int r = 0; r < 4; ++r) {
                int row = row0 + wr128 + i * 16 + cr + r;
                float v = acc[i][j][r] + bv;
                if (DO_GELU) {
                    float u = 0.7978845608f * v * (1.f + 0.044715f * v * v);
                    v = v / (1.f + __expf(-2.f * u));
                }
                C[(size_t)row * N + col] = bf16rne(v);
            }
        }
    }
}

// ---------------- Combine: out = w0*expOut[e0,s0] + w1*expOut[e1,s1] ----------
__global__ void combine_kernel(const int* __restrict__ r_eidx,
                               const float* __restrict__ r_w,
                               const int* __restrict__ assign_slot,
                               const u16* __restrict__ exp_out,
                               float* __restrict__ out) {
    const int t = blockIdx.x;
    const int d = threadIdx.x * 4;
    const int e0 = r_eidx[t], e1 = r_eidx[N_TOK + t];
    const float w0 = r_w[t], w1 = r_w[N_TOK + t];
    const int s0 = assign_slot[t], s1 = assign_slot[N_TOK + t];
    float v0 = 0.f, v1 = 0.f, v2 = 0.f, v3 = 0.f;
    if (s0 >= 0) {
        const u16* p = exp_out + ((size_t)e0 * CAP + s0) * DIM + d;
        ushort4 q = *(const ushort4*)p;
        v0 += w0 * bf2f(q.x); v1 += w0 * bf2f(q.y);
        v2 += w0 * bf2f(q.z); v3 += w0 * bf2f(q.w);
    }
    if (s1 >= 0) {
        const u16* p = exp_out + ((size_t)e1 * CAP + s1) * DIM + d;
        ushort4 q = *(const ushort4*)p;
        v0 += w1 * bf2f(q.x); v1 += w1 * bf2f(q.y);
        v2 += w1 * bf2f(q.z); v3 += w1 * bf2f(q.w);
    }
    float4 o; o.x = v0; o.y = v1; o.z = v2; o.w = v3;
    *(float4*)(out + (size_t)t * DIM + d) = o;
}

// ---------------- Launch ----------------
extern "C" void kernel_launch(void* const* d_in, const int* in_sizes, int n_in,
                              void* d_out, int out_size, void* d_ws, size_t ws_size,
                              hipStream_t stream) {
    const float* x         = (const float*)d_in[0];
    const float* gate_w    = (const float*)d_in[1];
    const float* c_fc      = (const float*)d_in[2];
    const float* fc_bias   = (const float*)d_in[3];
    const float* c_proj    = (const float*)d_in[4];
    const float* proj_bias = (const float*)d_in[5];
    float* out = (float*)d_out;
    char* ws = (char*)d_ws;

    // workspace layout (bytes)
    int*   r_eidx         = (int*)(ws + 0);              //  32 KB
    float* r_w            = (float*)(ws + 32768);        //  32 KB
    int*   assign_slot    = (int*)(ws + 65536);          //  32 KB
    int*   token_for_slot = (int*)(ws + 98304);          //  40 KB
    int*   used           = (int*)(ws + 139264);         //  32 B (pad to 24 KB)
    u16*   exp_batches    = (u16*)(ws + 163840);         //  20.97 MB [10240,1024]
    u16*   exp_out        = exp_batches;                 //  aliased (dead after GEMM1)
    u16*   h              = (u16*)(ws + 21135360);       //  83.9  MB [10240,4096]
    u16*   Bt             = (u16*)(ws + 105021440);      //  64 MB (Bt1 then Bt2)
    // total: 172,130,304 bytes (~164 MB)

    router_kernel<<<N_TOK / 4, 256, 0, stream>>>(x, gate_w, r_eidx, r_w);
    assign_kernel<<<1, 1024, 0, stream>>>(r_eidx, assign_slot, token_for_slot, used);
    gather_kernel<<<N_EXP * CAP, 256, 0, stream>>>(x, token_for_slot, exp_batches);

    // Bt1 = c_fc^T per expert: [D,H] -> [H,D]
    transpose_cvt<<<dim3(HID / 64, DIM / 64, N_EXP), 256, 0, stream>>>(
        c_fc, Bt, DIM, HID);
    moe_gemm8<true><<<(HID / 256) * (CAP / 256) * N_EXP, 512, 0, stream>>>(
        exp_batches, Bt, fc_bias, h, used, HID, DIM);

    // Bt2 = c_proj^T per expert: [H,D] -> [D,H]  (aliases Bt1, now dead)
    transpose_cvt<<<dim3(DIM / 64, HID / 64, N_EXP), 256, 0, stream>>>(
        c_proj, Bt, HID, DIM);
    moe_gemm8<false><<<(DIM / 256) * (CAP / 256) * N_EXP, 512, 0, stream>>>(
        h, Bt, proj_bias, exp_out, used, DIM, HID);

    combine_kernel<<<N_TOK, 256, 0, stream>>>(r_eidx, r_w, assign_slot, exp_out, out);
}

// Round 2
// 559.700 us; speedup vs baseline: 1.1740x; 1.1740x over previous
//
#include <hip/hip_runtime.h>
#include <hip/hip_bf16.h>

typedef unsigned short u16;
typedef unsigned int u32;

#define N_TOK 4096
#define DIM   1024
#define HID   4096
#define N_EXP 8
#define CAP   1280

typedef short short8 __attribute__((ext_vector_type(8)));
typedef float f32x4 __attribute__((ext_vector_type(4)));

__device__ __forceinline__ u16 bf16rne(float f) {
    u32 u = __float_as_uint(f);
    u32 r = u + 0x7FFFu + ((u >> 16) & 1u);
    return (u16)(r >> 16);
}
__device__ __forceinline__ float bf2f(u16 h) {
    return __uint_as_float(((u32)h) << 16);
}

#define GLDS(gp, lp) __builtin_amdgcn_global_load_lds( \
    (const __attribute__((address_space(1))) void*)(gp), \
    (__attribute__((address_space(3))) void*)(lp), 16, 0, 0)

#define SBAR  asm volatile("s_barrier" ::: "memory")
#define LGKM0 asm volatile("s_waitcnt lgkmcnt(0)" ::: "memory")
#define VMW8  asm volatile("s_waitcnt vmcnt(8)" ::: "memory")
#define VMW5  asm volatile("s_waitcnt vmcnt(5)" ::: "memory")
#define VMW0  asm volatile("s_waitcnt vmcnt(0)" ::: "memory")

// ---------------- Router: one wave per token ----------------
__global__ void router_kernel(const float* __restrict__ x,
                              const float* __restrict__ gw,
                              int* __restrict__ r_eidx,
                              float* __restrict__ r_w) {
    const int wave = threadIdx.x >> 6, lane = threadIdx.x & 63;
    const int t = blockIdx.x * 4 + wave;
    const float* xr = x + (size_t)t * DIM;
    float acc[8];
#pragma unroll
    for (int e = 0; e < 8; e++) acc[e] = 0.f;
#pragma unroll 4
    for (int i = 0; i < DIM / 64; i++) {
        int d = i * 64 + lane;
        float xv = xr[d];
        const float4* g = (const float4*)(gw + (size_t)d * 8);
        float4 g0 = g[0], g1 = g[1];
        acc[0] += xv * g0.x; acc[1] += xv * g0.y;
        acc[2] += xv * g0.z; acc[3] += xv * g0.w;
        acc[4] += xv * g1.x; acc[5] += xv * g1.y;
        acc[6] += xv * g1.z; acc[7] += xv * g1.w;
    }
#pragma unroll
    for (int e = 0; e < 8; e++) {
#pragma unroll
        for (int off = 32; off > 0; off >>= 1)
            acc[e] += __shfl_xor(acc[e], off, 64);
    }
    if (lane == 0) {
        int e0 = 0; float l0 = acc[0];
#pragma unroll
        for (int e = 1; e < 8; e++) if (acc[e] > l0) { l0 = acc[e]; e0 = e; }
        int e1 = -1; float l1 = -1e30f;
#pragma unroll
        for (int e = 0; e < 8; e++) if (e != e0 && acc[e] > l1) { l1 = acc[e]; e1 = e; }
        float z = __expf(l1 - l0);          // <= 1
        float inv = 1.f / (1.f + z);
        r_eidx[t] = e0; r_eidx[N_TOK + t] = e1;
        r_w[t] = inv;   r_w[N_TOK + t] = z * inv;
    }
}

// ---------------- Capacity assignment: single block, deterministic scan ------
__global__ void assign_kernel(const int* __restrict__ r_eidx,
                              int* __restrict__ assign_slot,
                              int* __restrict__ token_for_slot,
                              int* __restrict__ used) {
    const int tid = threadIdx.x;                 // 0..1023
    __shared__ int wtot[8][16];
    __shared__ int wbase[8][16];
    for (int i = tid; i < N_EXP * CAP; i += 1024) token_for_slot[i] = -1;

    int le[8], lr[8], cnt[8];
#pragma unroll
    for (int e = 0; e < 8; e++) cnt[e] = 0;
#pragma unroll
    for (int j = 0; j < 8; j++) {
        int e = r_eidx[tid * 8 + j];
        le[j] = e;
        int r = 0;
#pragma unroll
        for (int e2 = 0; e2 < 8; e2++)
            if (e == e2) { r = cnt[e2]; cnt[e2] = r + 1; }
        lr[j] = r;
    }
    const int lane = tid & 63, wv = tid >> 6;    // 16 waves
    int excl[8];
#pragma unroll
    for (int e = 0; e < 8; e++) {
        int v = cnt[e], inc = v;
#pragma unroll
        for (int off = 1; off < 64; off <<= 1) {
            int u = __shfl_up(inc, off, 64);
            if (lane >= off) inc += u;
        }
        excl[e] = inc - v;
        if (lane == 63) wtot[e][wv] = inc;
    }
    __syncthreads();
    if (tid < 8) {
        int s = 0;
        for (int w = 0; w < 16; w++) { wbase[tid][w] = s; s += wtot[tid][w]; }
        used[tid] = s < CAP ? s : CAP;
    }
    __syncthreads();
#pragma unroll
    for (int j = 0; j < 8; j++) {
        int i = tid * 8 + j;
        int e = le[j];
        int b = 0;
#pragma unroll
        for (int e2 = 0; e2 < 8; e2++)
            if (e == e2) b = wbase[e2][wv] + excl[e2];
        int rank = b + lr[j];
        int tok = i & (N_TOK - 1);
        if (rank < CAP) {
            assign_slot[i] = rank;
            token_for_slot[e * CAP + rank] = tok;
        } else {
            assign_slot[i] = -1;
        }
    }
}

// ---------------- Gather tokens into per-expert batches (bf16) ----------------
__global__ void gather_kernel(const float* __restrict__ x,
                              const int* __restrict__ token_for_slot,
                              u16* __restrict__ exp_batches) {
    const int s = blockIdx.x;
    const int tok = token_for_slot[s];
    const int d = threadIdx.x * 4;
    ushort4 o;
    if (tok >= 0) {
        float4 v = *(const float4*)(x + (size_t)tok * DIM + d);
        o = make_ushort4(bf16rne(v.x), bf16rne(v.y), bf16rne(v.z), bf16rne(v.w));
    } else {
        o = make_ushort4(0, 0, 0, 0);
    }
    *(ushort4*)(exp_batches + (size_t)s * DIM + d) = o;
}

// ---------------- Weight transpose+convert: f32 [R][C] -> bf16 [C][R] --------
__global__ __launch_bounds__(256) void transpose_cvt(
    const float* __restrict__ in, u16* __restrict__ out, int R, int C) {
    __shared__ float t[64][65];
    const int ez = blockIdx.z;
    in  += (size_t)ez * R * C;
    out += (size_t)ez * R * C;
    const int row0 = blockIdx.y * 64, col0 = blockIdx.x * 64;
    const int tid = threadIdx.x;
    {
        const int r = tid >> 2, cq = (tid & 3) * 16;
        const float* p = in + (size_t)(row0 + r) * C + col0 + cq;
        float4 v0 = ((const float4*)p)[0];
        float4 v1 = ((const float4*)p)[1];
        float4 v2 = ((const float4*)p)[2];
        float4 v3 = ((const float4*)p)[3];
        float tmp[16] = {v0.x, v0.y, v0.z, v0.w, v1.x, v1.y, v1.z, v1.w,
                         v2.x, v2.y, v2.z, v2.w, v3.x, v3.y, v3.z, v3.w};
#pragma unroll
        for (int j = 0; j < 16; j++) t[r][cq + j] = tmp[j];
    }
    __syncthreads();
    {
        const int oc = tid >> 2, h4 = (tid & 3) * 16;
        u16 o[16];
#pragma unroll
        for (int i = 0; i < 16; i++) o[i] = bf16rne(t[h4 + i][oc]);
        u16* q = out + (size_t)(col0 + oc) * R + row0 + h4;
        *(uint4*)q = *(const uint4*)&o[0];
        *(uint4*)(q + 8) = *(const uint4*)&o[8];
    }
}

// ---------------- MFMA GEMM: BM x 256 tile, BK=64, 2-deep counted-vmcnt ------
// A: [CAP,K] bf16 row-major per expert.  Bt: [N,K] bf16 row-major.
// LDS scheme = round-0's proven 0-conflict one: per tile-buffer, A rows then
// B rows, each row = 64 u16 = 128B; within a row the 8 16B k-chunks are
// XOR-swizzled by (row&7) in the GLOBAL source address (DMA-legal, involution)
// and un-swizzled on the ds_read side.  Staging: each wave-load covers 8 full
// rows (8 lanes x 16B per row) -> fully coalesced 128B runs.
// Schedule (T3 minimum + T4 counted): per K-tile of 64:
//   {24 ds_read_b128 + (MI*8) MFMA}  -> lgkmcnt(0); s_barrier;
//   issue next+2 tile's GLDS into the buffer just consumed;
//   s_waitcnt vmcnt(L)  (L = this wave's loads/tile; NEVER 0 mid-loop);
//   s_barrier.
// 2 buffers, prefetch distance 2 tiles: a load issued at end of tile t is
// needed at tile t+2 -> one full tile of MFMA latency cover.
// Waves: 8 = 2(M) x 4(N).  mh = wave>>2 doubles as staging role (A vs B).
// K accumulation order identical to the 554us baseline -> bit-identical output.
template <int BM, bool DO_GELU>
__global__ __launch_bounds__(512, 2) void moe_gemm256(
    const u16* __restrict__ A, const u16* __restrict__ Bt,
    const float* __restrict__ bias, u16* __restrict__ C,
    const int* __restrict__ used, int N, int K) {
    constexpr int MI   = BM / 32;            // per-wave M frags (8 or 5)
    constexpr int ALW  = BM / 32;            // A-loads per A-wave per tile
    constexpr int BUFE = (BM + 256) * 64;    // u16 per tile buffer
    constexpr int NROW = CAP / BM;
    __shared__ __align__(16) u16 lds[2 * BUFE];

    const int NT = K >> 6;
    const int bid = blockIdx.x;
    const int e = bid & 7;                   // expert == XCD affinity
    const int local = bid >> 3;
    const int row0 = (local % NROW) * BM;    // row-fastest within XCD
    const int col0 = (local / NROW) * 256;
    if (row0 >= used[e]) return;             // uniform per block

    A    += (size_t)e * CAP * K;
    Bt   += (size_t)e * N * K;
    bias += (size_t)e * N;
    C    += (size_t)e * CAP * N;

    const int tid = threadIdx.x;
    const int lane = tid & 63, wave = tid >> 6;
    const int mh   = wave >> 2;              // M-half AND staging role (0=A,1=B)
    const int wv4  = wave & 3;
    const int wr   = mh * (BM / 2);
    const int wc64 = wv4 * 64;

    // ---- staging geometry (round-0 scheme) ----
    const int srow = lane >> 3;              // row within 8-row group
    const int swz  = ((lane & 7) ^ srow) * 8;  // XOR k-chunk swizzle (global side)
    const int LW   = mh ? 8 : ALW;           // loads per wave per tile
    const int ro0  = wv4 * LW * 8;           // first row this wave stages
    const u16* gsrc = (mh ? Bt + (size_t)(col0 + ro0 + srow) * K
                          : A  + (size_t)(row0 + ro0 + srow) * K) + swz;
    u16* dbase = lds + (mh ? BM * 64 : 0) + ro0 * 64;

    auto stage = [&](int buf, int kt) {
        u16* db = dbase + (size_t)buf * BUFE;
        const u16* sb = gsrc + kt;
        if (mh) {
#pragma unroll
            for (int i = 0; i < 8; ++i)
                GLDS(sb + (size_t)(i * 8) * K, db + i * 512);
        } else {
#pragma unroll
            for (int i = 0; i < ALW; ++i)
                GLDS(sb + (size_t)(i * 8) * K, db + i * 512);
        }
    };
    auto waitL = [&]() {
        if constexpr (ALW == 8) { VMW8; }
        else { if (mh) { VMW8; } else { VMW5; } }
    };

    f32x4 acc[MI][4];
#pragma unroll
    for (int i = 0; i < MI; i++)
#pragma unroll
        for (int j = 0; j < 4; j++) acc[i][j] = (f32x4){0.f, 0.f, 0.f, 0.f};

    // ---- prologue: stage tiles 0 and 1, wait tile 0 ----
    stage(0, 0);
    stage(1, 64);
    waitL();
    SBAR;

    // ---- fragment-read geometry ----
    const int rrd = lane & 15, qrd = lane >> 4;
    const int k0 = ((qrd ^ (rrd & 7)) << 3);          // swizzled k-off, ks=0
    const int k1 = (((4 + qrd) ^ (rrd & 7)) << 3);    // swizzled k-off, ks=1
    const int aoff = (wr + rrd) * 64;
    const int boff = (wc64 + rrd) * 64;

    for (int t = 0; t < NT; ++t) {
        const u16* As = lds + (size_t)(t & 1) * BUFE;
        const u16* Bs = As + BM * 64;

        short8 bf0[4], bf1[4];
#pragma unroll
        for (int j = 0; j < 4; ++j) {
            bf0[j] = *(const short8*)(Bs + boff + j * 1024 + k0);
            bf1[j] = *(const short8*)(Bs + boff + j * 1024 + k1);
        }
#pragma unroll
        for (int i = 0; i < MI; ++i) {
            short8 a0 = *(const short8*)(As + aoff + i * 1024 + k0);
            short8 a1 = *(const short8*)(As + aoff + i * 1024 + k1);
            __builtin_amdgcn_s_setprio(1);
#pragma unroll
            for (int j = 0; j < 4; ++j)
                acc[i][j] = __builtin_amdgcn_mfma_f32_16x16x32_bf16(
                    a0, bf0[j], acc[i][j], 0, 0, 0);
#pragma unroll
            for (int j = 0; j < 4; ++j)
                acc[i][j] = __builtin_amdgcn_mfma_f32_16x16x32_bf16(
                    a1, bf1[j], acc[i][j], 0, 0, 0);
            __builtin_amdgcn_s_setprio(0);
        }

        if (t < NT - 1) {
            LGKM0;                                    // this wave's reads done
            __builtin_amdgcn_sched_barrier(0);        // rule-18 fence
            SBAR;                                     // all waves' reads done
            if (t + 2 < NT) { stage(t & 1, (t + 2) * 64); waitL(); }
            else            { VMW0; }                 // only at loop tail
            SBAR;                                     // tile t+1 visible to all
        }
    }

    // ---- epilogue: bias (+gelu) -> bf16, j-INNER so each 128B line is
    // written by 4 back-to-back stores (no partial-line writeback RMW) ----
    const int cr = qrd * 4;
    const int cc = rrd;
    float bv[4];
#pragma unroll
    for (int j = 0; j < 4; ++j) bv[j] = bias[col0 + wc64 + j * 16 + cc];
#pragma unroll
    for (int i = 0; i < MI; ++i) {
#pragma unroll
        for (int r = 0; r < 4; ++r) {
            const int row = row0 + wr + i * 16 + cr + r;
            u16* cp = C + (size_t)row * N + col0 + wc64 + cc;
#pragma unroll
            for (int j = 0; j < 4; ++j) {
                float v = acc[i][j][r] + bv[j];
                if (DO_GELU) {
                    float u = 0.7978845608f * v * (1.f + 0.044715f * v * v);
                    v = v / (1.f + __expf(-2.f * u));
                }
                cp[j * 16] = bf16rne(v);
            }
        }
    }
}

// ---------------- Combine: out = w0*expOut[e0,s0] + w1*expOut[e1,s1] ----------
__global__ void combine_kernel(const int* __restrict__ r_eidx,
                               const float* __restrict__ r_w,
                               const int* __restrict__ assign_slot,
                               const u16* __restrict__ exp_out,
                               float* __restrict__ out) {
    const int t = blockIdx.x;
    const int d = threadIdx.x * 4;
    const int e0 = r_eidx[t], e1 = r_eidx[N_TOK + t];
    const float w0 = r_w[t], w1 = r_w[N_TOK + t];
    const int s0 = assign_slot[t], s1 = assign_slot[N_TOK + t];
    float v0 = 0.f, v1 = 0.f, v2 = 0.f, v3 = 0.f;
    if (s0 >= 0) {
        const u16* p = exp_out + ((size_t)e0 * CAP + s0) * DIM + d;
        ushort4 q = *(const ushort4*)p;
        v0 += w0 * bf2f(q.x); v1 += w0 * bf2f(q.y);
        v2 += w0 * bf2f(q.z); v3 += w0 * bf2f(q.w);
    }
    if (s1 >= 0) {
        const u16* p = exp_out + ((size_t)e1 * CAP + s1) * DIM + d;
        ushort4 q = *(const ushort4*)p;
        v0 += w1 * bf2f(q.x); v1 += w1 * bf2f(q.y);
        v2 += w1 * bf2f(q.z); v3 += w1 * bf2f(q.w);
    }
    float4 o; o.x = v0; o.y = v1; o.z = v2; o.w = v3;
    *(float4*)(out + (size_t)t * DIM + d) = o;
}

// ---------------- Launch ----------------
extern "C" void kernel_launch(void* const* d_in, const int* in_sizes, int n_in,
                              void* d_out, int out_size, void* d_ws, size_t ws_size,
                              hipStream_t stream) {
    const float* x         = (const float*)d_in[0];
    const float* gate_w    = (const float*)d_in[1];
    const float* c_fc      = (const float*)d_in[2];
    const float* fc_bias   = (const float*)d_in[3];
    const float* c_proj    = (const float*)d_in[4];
    const float* proj_bias = (const float*)d_in[5];
    float* out = (float*)d_out;
    char* ws = (char*)d_ws;

    // workspace layout (bytes)
    int*   r_eidx         = (int*)(ws + 0);              //  32 KB
    float* r_w            = (float*)(ws + 32768);        //  32 KB
    int*   assign_slot    = (int*)(ws + 65536);          //  32 KB
    int*   token_for_slot = (int*)(ws + 98304);          //  40 KB
    int*   used           = (int*)(ws + 139264);         //  32 B (pad to 24 KB)
    u16*   exp_batches    = (u16*)(ws + 163840);         //  20.97 MB [10240,1024]
    u16*   exp_out        = exp_batches;                 //  aliased (dead after GEMM1)
    u16*   h              = (u16*)(ws + 21135360);       //  83.9  MB [10240,4096]
    u16*   Bt             = (u16*)(ws + 105021440);      //  64 MB (Bt1 then Bt2)
    // total: 172,130,304 bytes (~164 MB)

    router_kernel<<<N_TOK / 4, 256, 0, stream>>>(x, gate_w, r_eidx, r_w);
    assign_kernel<<<1, 1024, 0, stream>>>(r_eidx, assign_slot, token_for_slot, used);
    gather_kernel<<<N_EXP * CAP, 256, 0, stream>>>(x, token_for_slot, exp_batches);

    // Bt1 = c_fc^T per expert: [D,H] -> [H,D]
    transpose_cvt<<<dim3(HID / 64, DIM / 64, N_EXP), 256, 0, stream>>>(
        c_fc, Bt, DIM, HID);
    // GEMM1: [CAP,1024] x [4096,1024]^T, BM=256 -> 5x16x8 = 640 blocks
    moe_gemm256<256, true><<<(CAP / 256) * (HID / 256) * N_EXP, 512, 0, stream>>>(
        exp_batches, Bt, fc_bias, h, used, HID, DIM);

    // Bt2 = c_proj^T per expert: [H,D] -> [D,H]  (aliases Bt1, now dead)
    transpose_cvt<<<dim3(DIM / 64, HID / 64, N_EXP), 256, 0, stream>>>(
        c_proj, Bt, HID, DIM);
    // GEMM2: [CAP,4096] x [1024,4096]^T, BM=160 -> 8x4x8 = 256 blocks (1/CU)
    moe_gemm256<160, false><<<(CAP / 160) * (DIM / 256) * N_EXP, 512, 0, stream>>>(
        h, Bt, proj_bias, exp_out, used, DIM, HID);

    combine_kernel<<<N_TOK, 256, 0, stream>>>(r_eidx, r_w, assign_slot, exp_out, out);
}

// Round 3
// 559.051 us; speedup vs baseline: 1.1753x; 1.0012x over previous
//
#include <hip/hip_runtime.h>
#include <hip/hip_bf16.h>

typedef unsigned short u16;
typedef unsigned int u32;

#define N_TOK 4096
#define DIM   1024
#define HID   4096
#define N_EXP 8
#define CAP   1280

typedef short short8 __attribute__((ext_vector_type(8)));
typedef float f32x4 __attribute__((ext_vector_type(4)));

__device__ __forceinline__ u16 bf16rne(float f) {
    u32 u = __float_as_uint(f);
    u32 r = u + 0x7FFFu + ((u >> 16) & 1u);
    return (u16)(r >> 16);
}
__device__ __forceinline__ float bf2f(u16 h) {
    return __uint_as_float(((u32)h) << 16);
}

#define GLDS(gp, lp) __builtin_amdgcn_global_load_lds( \
    (const __attribute__((address_space(1))) void*)(gp), \
    (__attribute__((address_space(3))) void*)(lp), 16, 0, 0)

#define SBAR  asm volatile("s_barrier" ::: "memory")
#define LGKM0 asm volatile("s_waitcnt lgkmcnt(0)" ::: "memory")
#define VMW8  asm volatile("s_waitcnt vmcnt(8)" ::: "memory")
#define VMW5  asm volatile("s_waitcnt vmcnt(5)" ::: "memory")
#define VMW0  asm volatile("s_waitcnt vmcnt(0)" ::: "memory")

// ---------------- Router: one wave per token ----------------
__global__ void router_kernel(const float* __restrict__ x,
                              const float* __restrict__ gw,
                              int* __restrict__ r_eidx,
                              float* __restrict__ r_w) {
    const int wave = threadIdx.x >> 6, lane = threadIdx.x & 63;
    const int t = blockIdx.x * 4 + wave;
    const float* xr = x + (size_t)t * DIM;
    float acc[8];
#pragma unroll
    for (int e = 0; e < 8; e++) acc[e] = 0.f;
#pragma unroll 4
    for (int i = 0; i < DIM / 64; i++) {
        int d = i * 64 + lane;
        float xv = xr[d];
        const float4* g = (const float4*)(gw + (size_t)d * 8);
        float4 g0 = g[0], g1 = g[1];
        acc[0] += xv * g0.x; acc[1] += xv * g0.y;
        acc[2] += xv * g0.z; acc[3] += xv * g0.w;
        acc[4] += xv * g1.x; acc[5] += xv * g1.y;
        acc[6] += xv * g1.z; acc[7] += xv * g1.w;
    }
#pragma unroll
    for (int e = 0; e < 8; e++) {
#pragma unroll
        for (int off = 32; off > 0; off >>= 1)
            acc[e] += __shfl_xor(acc[e], off, 64);
    }
    if (lane == 0) {
        int e0 = 0; float l0 = acc[0];
#pragma unroll
        for (int e = 1; e < 8; e++) if (acc[e] > l0) { l0 = acc[e]; e0 = e; }
        int e1 = -1; float l1 = -1e30f;
#pragma unroll
        for (int e = 0; e < 8; e++) if (e != e0 && acc[e] > l1) { l1 = acc[e]; e1 = e; }
        float z = __expf(l1 - l0);          // <= 1
        float inv = 1.f / (1.f + z);
        r_eidx[t] = e0; r_eidx[N_TOK + t] = e1;
        r_w[t] = inv;   r_w[N_TOK + t] = z * inv;
    }
}

// ---------------- Capacity assignment: single block, deterministic scan ------
__global__ void assign_kernel(const int* __restrict__ r_eidx,
                              int* __restrict__ assign_slot,
                              int* __restrict__ token_for_slot,
                              int* __restrict__ used) {
    const int tid = threadIdx.x;                 // 0..1023
    __shared__ int wtot[8][16];
    __shared__ int wbase[8][16];
    for (int i = tid; i < N_EXP * CAP; i += 1024) token_for_slot[i] = -1;

    int le[8], lr[8], cnt[8];
#pragma unroll
    for (int e = 0; e < 8; e++) cnt[e] = 0;
#pragma unroll
    for (int j = 0; j < 8; j++) {
        int e = r_eidx[tid * 8 + j];
        le[j] = e;
        int r = 0;
#pragma unroll
        for (int e2 = 0; e2 < 8; e2++)
            if (e == e2) { r = cnt[e2]; cnt[e2] = r + 1; }
        lr[j] = r;
    }
    const int lane = tid & 63, wv = tid >> 6;    // 16 waves
    int excl[8];
#pragma unroll
    for (int e = 0; e < 8; e++) {
        int v = cnt[e], inc = v;
#pragma unroll
        for (int off = 1; off < 64; off <<= 1) {
            int u = __shfl_up(inc, off, 64);
            if (lane >= off) inc += u;
        }
        excl[e] = inc - v;
        if (lane == 63) wtot[e][wv] = inc;
    }
    __syncthreads();
    if (tid < 8) {
        int s = 0;
        for (int w = 0; w < 16; w++) { wbase[tid][w] = s; s += wtot[tid][w]; }
        used[tid] = s < CAP ? s : CAP;
    }
    __syncthreads();
#pragma unroll
    for (int j = 0; j < 8; j++) {
        int i = tid * 8 + j;
        int e = le[j];
        int b = 0;
#pragma unroll
        for (int e2 = 0; e2 < 8; e2++)
            if (e == e2) b = wbase[e2][wv] + excl[e2];
        int rank = b + lr[j];
        int tok = i & (N_TOK - 1);
        if (rank < CAP) {
            assign_slot[i] = rank;
            token_for_slot[e * CAP + rank] = tok;
        } else {
            assign_slot[i] = -1;
        }
    }
}

// ---------------- Gather tokens into per-expert batches (bf16) ----------------
__global__ void gather_kernel(const float* __restrict__ x,
                              const int* __restrict__ token_for_slot,
                              u16* __restrict__ exp_batches) {
    const int s = blockIdx.x;
    const int tok = token_for_slot[s];
    const int d = threadIdx.x * 4;
    ushort4 o;
    if (tok >= 0) {
        float4 v = *(const float4*)(x + (size_t)tok * DIM + d);
        o = make_ushort4(bf16rne(v.x), bf16rne(v.y), bf16rne(v.z), bf16rne(v.w));
    } else {
        o = make_ushort4(0, 0, 0, 0);
    }
    *(ushort4*)(exp_batches + (size_t)s * DIM + d) = o;
}

// ---------------- Weight transpose+convert: f32 [R][C] -> bf16 [C][R] --------
__global__ __launch_bounds__(256) void transpose_cvt(
    const float* __restrict__ in, u16* __restrict__ out, int R, int C) {
    __shared__ float t[64][65];
    const int ez = blockIdx.z;
    in  += (size_t)ez * R * C;
    out += (size_t)ez * R * C;
    const int row0 = blockIdx.y * 64, col0 = blockIdx.x * 64;
    const int tid = threadIdx.x;
    {
        const int r = tid >> 2, cq = (tid & 3) * 16;
        const float* p = in + (size_t)(row0 + r) * C + col0 + cq;
        float4 v0 = ((const float4*)p)[0];
        float4 v1 = ((const float4*)p)[1];
        float4 v2 = ((const float4*)p)[2];
        float4 v3 = ((const float4*)p)[3];
        float tmp[16] = {v0.x, v0.y, v0.z, v0.w, v1.x, v1.y, v1.z, v1.w,
                         v2.x, v2.y, v2.z, v2.w, v3.x, v3.y, v3.z, v3.w};
#pragma unroll
        for (int j = 0; j < 16; j++) t[r][cq + j] = tmp[j];
    }
    __syncthreads();
    {
        const int oc = tid >> 2, h4 = (tid & 3) * 16;
        u16 o[16];
#pragma unroll
        for (int i = 0; i < 16; i++) o[i] = bf16rne(t[h4 + i][oc]);
        u16* q = out + (size_t)(col0 + oc) * R + row0 + h4;
        *(uint4*)q = *(const uint4*)&o[0];
        *(uint4*)(q + 8) = *(const uint4*)&o[8];
    }
}

// ---------------- MFMA GEMM: persistent BMx256 tiles, BK=64, counted vmcnt ---
// A: [CAP,K] bf16 row-major per expert.  Bt: [N,K] bf16 row-major.
// Grid is always 256 blocks (1 per CU, 32 per XCD, expert = bid&7 -> XCD
// affinity).  Each block owns ONE 256-wide B-column panel and processes TPB
// row-tiles of height BM against it (persistent), interleaved rows
// (rgrp + q*RB) for early-exit balance.  Pipeline: 2 LDS buffers, prefetch
// distance 2 K-tiles; at the last two K-iters of a tile, the NEXT tile's
// k-tiles 0/1 are staged into the just-freed buffers (NT even -> parity
// matches), so the epilogue (no LDS, no barrier) overlaps the next tile's
// fill.  vmcnt waits are counted (VMW5/VMW8), never 0 mid-pipeline; the
// tile-top wait also covers older epilogue stores (conservative, safe).
// LDS scheme = round-0's proven 0-conflict one (XOR k-chunk swizzle applied
// on the GLOBAL source address, involution, un-swizzled on ds_read side).
// K accumulation order identical to baseline -> bit-identical output.
template <int BM, int TPB, bool DO_GELU>
__global__ __launch_bounds__(512, 2) void moe_gemmP(
    const u16* __restrict__ A, const u16* __restrict__ Bt,
    const float* __restrict__ bias, u16* __restrict__ C,
    const int* __restrict__ used, int N, int K) {
    constexpr int MI    = BM / 32;           // per-wave M frags
    constexpr int ALW   = BM / 32;           // A-loads per A-wave per k-tile
    constexpr int BUFE  = (BM + 256) * 64;   // u16 per tile buffer
    constexpr int NROWT = CAP / BM;          // row tiles total
    constexpr int RB    = NROWT / TPB;       // blocks per column panel
    __shared__ __align__(16) u16 lds[2 * BUFE];

    const int NT = K >> 6;                   // K-tiles of 64 (even)
    const int bid = blockIdx.x;
    const int e = bid & 7;                   // expert == XCD affinity
    const int local = bid >> 3;              // 0..31
    const int col0 = (local / RB) * 256;
    const int rgrp = local % RB;

    const int u = used[e];
    int nact = 0;
#pragma unroll
    for (int q = 0; q < TPB; ++q)
        if ((rgrp + q * RB) * BM < u) nact = q + 1;
    if (nact == 0) return;

    A    += (size_t)e * CAP * K;
    Bt   += (size_t)e * N * K;
    bias += (size_t)e * N;
    C    += (size_t)e * CAP * N;

    const int tid = threadIdx.x;
    const int lane = tid & 63, wave = tid >> 6;
    const int mh   = wave >> 2;              // M-half AND staging role (0=A,1=B)
    const int wv4  = wave & 3;
    const int wr   = mh * (BM / 2);
    const int wc64 = wv4 * 64;

    // ---- staging geometry ----
    const int srow = lane >> 3;
    const int swz  = ((lane & 7) ^ srow) * 8;
    const int LW   = mh ? 8 : ALW;
    const int ro0  = wv4 * LW * 8;
    int row0 = rgrp * BM;
    const size_t astep = (size_t)RB * BM * K;     // A advance per tile
    const u16* gp = (mh ? Bt + (size_t)(col0 + ro0 + srow) * K
                        : A  + (size_t)(row0 + ro0 + srow) * K) + swz;
    const size_t nextoff = mh ? 0 : astep;        // B panel is reused
    u16* dbase = lds + (mh ? BM * 64 : 0) + ro0 * 64;

    auto stage = [&](int buf, const u16* sb) {
        u16* db = dbase + (size_t)buf * BUFE;
        if (mh) {
#pragma unroll
            for (int i = 0; i < 8; ++i)
                GLDS(sb + (size_t)(i * 8) * K, db + i * 512);
        } else {
#pragma unroll
            for (int i = 0; i < ALW; ++i)
                GLDS(sb + (size_t)(i * 8) * K, db + i * 512);
        }
    };
    auto waitL = [&]() {
        if constexpr (ALW == 8) { VMW8; }
        else { if (mh) { VMW8; } else { VMW5; } }
    };

    // ---- fragment-read geometry ----
    const int rrd = lane & 15, qrd = lane >> 4;
    const int k0 = ((qrd ^ (rrd & 7)) << 3);
    const int k1 = (((4 + qrd) ^ (rrd & 7)) << 3);
    const int aoff = (wr + rrd) * 64;
    const int boff = (wc64 + rrd) * 64;
    const int cr = qrd * 4;
    const int cc = rrd;

    float bv[4];
#pragma unroll
    for (int j = 0; j < 4; ++j) bv[j] = bias[col0 + wc64 + j * 16 + cc];

    f32x4 acc[MI][4];

    for (int tt = 0; ; ++tt) {
#pragma unroll
        for (int i = 0; i < MI; i++)
#pragma unroll
            for (int j = 0; j < 4; j++) acc[i][j] = (f32x4){0.f, 0.f, 0.f, 0.f};

        if (tt == 0) { stage(0, gp); stage(1, gp + 64); }
        waitL();
        SBAR;

        const bool hasnext = (tt + 1 < nact);

        for (int t = 0; t < NT; ++t) {
            const u16* As = lds + (size_t)(t & 1) * BUFE;
            const u16* Bs = As + BM * 64;

            short8 bf0[4], bf1[4];
#pragma unroll
            for (int j = 0; j < 4; ++j) {
                bf0[j] = *(const short8*)(Bs + boff + j * 1024 + k0);
                bf1[j] = *(const short8*)(Bs + boff + j * 1024 + k1);
            }
#pragma unroll
            for (int i = 0; i < MI; ++i) {
                short8 a0 = *(const short8*)(As + aoff + i * 1024 + k0);
                short8 a1 = *(const short8*)(As + aoff + i * 1024 + k1);
                __builtin_amdgcn_s_setprio(1);
#pragma unroll
                for (int j = 0; j < 4; ++j)
                    acc[i][j] = __builtin_amdgcn_mfma_f32_16x16x32_bf16(
                        a0, bf0[j], acc[i][j], 0, 0, 0);
#pragma unroll
                for (int j = 0; j < 4; ++j)
                    acc[i][j] = __builtin_amdgcn_mfma_f32_16x16x32_bf16(
                        a1, bf1[j], acc[i][j], 0, 0, 0);
                __builtin_amdgcn_s_setprio(0);
            }

            if (t < NT - 1) {
                LGKM0;                               // this wave's reads done
                __builtin_amdgcn_sched_barrier(0);   // rule-18 fence
                SBAR;                                // all waves' reads done
                const int idx = t + 2;
                if (idx < NT)     { stage(idx & 1, gp + idx * 64); waitL(); }
                else if (hasnext) { stage(0, gp + nextoff); waitL(); } // next k0
                else              { VMW0; }          // loop tail only
                SBAR;                                // tile t+1 visible
            } else if (hasnext) {
                LGKM0;                               // buf1 reads done
                __builtin_amdgcn_sched_barrier(0);
                SBAR;
                stage(1, gp + nextoff + 64);         // next tile's k1 -> buf1
                // no wait here: epilogue overlaps these loads; the next
                // tile-top waitL() guards k0, and t=0's in-loop waitL guards k1.
            }
        }

        // ---- epilogue: bias (+gelu) -> bf16, j-INNER (128B line in 4 stores)
#pragma unroll
        for (int i = 0; i < MI; ++i) {
#pragma unroll
            for (int r = 0; r < 4; ++r) {
                const int row = row0 + wr + i * 16 + cr + r;
                u16* cp = C + (size_t)row * N + col0 + wc64 + cc;
#pragma unroll
                for (int j = 0; j < 4; ++j) {
                    float v = acc[i][j][r] + bv[j];
                    if (DO_GELU) {
                        float uu = 0.7978845608f * v * (1.f + 0.044715f * v * v);
                        v = v / (1.f + __expf(-2.f * uu));
                    }
                    cp[j * 16] = bf16rne(v);
                }
            }
        }

        if (!hasnext) break;
        gp += nextoff;                // A waves advance; B waves stay
        row0 += RB * BM;
    }
}

// ---------------- Combine: out = w0*expOut[e0,s0] + w1*expOut[e1,s1] ----------
__global__ void combine_kernel(const int* __restrict__ r_eidx,
                               const float* __restrict__ r_w,
                               const int* __restrict__ assign_slot,
                               const u16* __restrict__ exp_out,
                               float* __restrict__ out) {
    const int t = blockIdx.x;
    const int d = threadIdx.x * 4;
    const int e0 = r_eidx[t], e1 = r_eidx[N_TOK + t];
    const float w0 = r_w[t], w1 = r_w[N_TOK + t];
    const int s0 = assign_slot[t], s1 = assign_slot[N_TOK + t];
    float v0 = 0.f, v1 = 0.f, v2 = 0.f, v3 = 0.f;
    if (s0 >= 0) {
        const u16* p = exp_out + ((size_t)e0 * CAP + s0) * DIM + d;
        ushort4 q = *(const ushort4*)p;
        v0 += w0 * bf2f(q.x); v1 += w0 * bf2f(q.y);
        v2 += w0 * bf2f(q.z); v3 += w0 * bf2f(q.w);
    }
    if (s1 >= 0) {
        const u16* p = exp_out + ((size_t)e1 * CAP + s1) * DIM + d;
        ushort4 q = *(const ushort4*)p;
        v0 += w1 * bf2f(q.x); v1 += w1 * bf2f(q.y);
        v2 += w1 * bf2f(q.z); v3 += w1 * bf2f(q.w);
    }
    float4 o; o.x = v0; o.y = v1; o.z = v2; o.w = v3;
    *(float4*)(out + (size_t)t * DIM + d) = o;
}

// ---------------- Launch ----------------
extern "C" void kernel_launch(void* const* d_in, const int* in_sizes, int n_in,
                              void* d_out, int out_size, void* d_ws, size_t ws_size,
                              hipStream_t stream) {
    const float* x         = (const float*)d_in[0];
    const float* gate_w    = (const float*)d_in[1];
    const float* c_fc      = (const float*)d_in[2];
    const float* fc_bias   = (const float*)d_in[3];
    const float* c_proj    = (const float*)d_in[4];
    const float* proj_bias = (const float*)d_in[5];
    float* out = (float*)d_out;
    char* ws = (char*)d_ws;

    // workspace layout (bytes)
    int*   r_eidx         = (int*)(ws + 0);              //  32 KB
    float* r_w            = (float*)(ws + 32768);        //  32 KB
    int*   assign_slot    = (int*)(ws + 65536);          //  32 KB
    int*   token_for_slot = (int*)(ws + 98304);          //  40 KB
    int*   used           = (int*)(ws + 139264);         //  32 B (pad to 24 KB)
    u16*   exp_batches    = (u16*)(ws + 163840);         //  20.97 MB [10240,1024]
    u16*   exp_out        = exp_batches;                 //  aliased (dead after GEMM1)
    u16*   h              = (u16*)(ws + 21135360);       //  83.9  MB [10240,4096]
    u16*   Bt             = (u16*)(ws + 105021440);      //  64 MB (Bt1 then Bt2)
    // total: 172,130,304 bytes (~164 MB)

    router_kernel<<<N_TOK / 4, 256, 0, stream>>>(x, gate_w, r_eidx, r_w);
    assign_kernel<<<1, 1024, 0, stream>>>(r_eidx, assign_slot, token_for_slot, used);
    gather_kernel<<<N_EXP * CAP, 256, 0, stream>>>(x, token_for_slot, exp_batches);

    // Bt1 = c_fc^T per expert: [D,H] -> [H,D]
    transpose_cvt<<<dim3(HID / 64, DIM / 64, N_EXP), 256, 0, stream>>>(
        c_fc, Bt, DIM, HID);
    // GEMM1: [CAP,1024] x [4096,1024]^T.  BM=160, TPB=4 -> 16 cols x 2 rgrp x 8
    // experts = 256 blocks (1/CU), 64 K-iters per block.
    moe_gemmP<160, 4, true><<<256, 512, 0, stream>>>(
        exp_batches, Bt, fc_bias, h, used, HID, DIM);

    // Bt2 = c_proj^T per expert: [H,D] -> [D,H]  (aliases Bt1, now dead)
    transpose_cvt<<<dim3(DIM / 64, HID / 64, N_EXP), 256, 0, stream>>>(
        c_proj, Bt, HID, DIM);
    // GEMM2: [CAP,4096] x [1024,4096]^T.  BM=160, TPB=1 -> 4 cols x 8 rgrp x 8
    // experts = 256 blocks (1/CU), 64 K-iters per block.
    moe_gemmP<160, 1, false><<<256, 512, 0, stream>>>(
        h, Bt, proj_bias, exp_out, used, DIM, HID);

    combine_kernel<<<N_TOK, 256, 0, stream>>>(r_eidx, r_w, assign_slot, exp_out, out);
}